// Round 1
// baseline (535.436 us; speedup 1.0000x reference)
//
#include <hip/hip_runtime.h>

#define DD    48
#define SP    (48*48*48)      // 110592 voxels
#define CIN   16
#define KOFF  18              // only first 2K offset channels are used (morph 0)
#define COUT  32
#define KK    9
#define NG    8               // groupnorm groups
#define EPSV  1e-5f

// ---------------------------------------------------------------------------
// Kernel 0: zero the stats buffer (ws is poisoned 0xAA before every launch)
// ---------------------------------------------------------------------------
__global__ __launch_bounds__(64) void k_zero(float* __restrict__ stats) {
    if (threadIdx.x < 2 * NG) stats[threadIdx.x] = 0.0f;
}

// ---------------------------------------------------------------------------
// Kernel 1: offset conv 3x3x3 (SAME, 16 -> 18 ch) + BN(eval) + tanh
// off layout: [co][d][w][h]  (co in 0..17; 0..8 = z-offsets, 9..17 = y-offsets)
// ---------------------------------------------------------------------------
__global__ __launch_bounds__(256) void k_offset(
    const float* __restrict__ x,  const float* __restrict__ ow,
    const float* __restrict__ ob, const float* __restrict__ bng,
    const float* __restrict__ bnb,const float* __restrict__ bnm,
    const float* __restrict__ bnv,float* __restrict__ off)
{
    // LDS weights, transposed to [tap][ci][co] with co padded to 20 so the
    // co-inner loop reads contiguous 16B-aligned runs (merges to ds_read_b128).
    __shared__ float wsm[27 * CIN * 20];   // 34.6 KB
    for (int i = threadIdx.x; i < 27 * CIN * KOFF; i += 256) {
        int co = i % KOFF; int r = i / KOFF; int ci = r % CIN; int tap = r / CIN;
        wsm[(tap * CIN + ci) * 20 + co] = ow[(co * CIN + ci) * 27 + tap];
    }
    __syncthreads();

    int v = blockIdx.x * 256 + threadIdx.x;
    int h = v % DD, w = (v / DD) % DD, d = v / (DD * DD);

    float acc[KOFF];
#pragma unroll
    for (int c = 0; c < KOFF; ++c) acc[c] = 0.0f;

#pragma unroll
    for (int kd = 0; kd < 3; ++kd) {
        int z = d + kd - 1; if ((unsigned)z >= (unsigned)DD) continue;
#pragma unroll
        for (int kw = 0; kw < 3; ++kw) {
            int yy = w + kw - 1; if ((unsigned)yy >= (unsigned)DD) continue;
#pragma unroll
            for (int kh = 0; kh < 3; ++kh) {
                int xx = h + kh - 1; if ((unsigned)xx >= (unsigned)DD) continue;
                int tap = (kd * 3 + kw) * 3 + kh;
                const float* xb = x + (z * DD + yy) * DD + xx;
                const float* wb = &wsm[tap * CIN * 20];
#pragma unroll
                for (int ci = 0; ci < CIN; ++ci) {
                    float val = xb[ci * SP];
                    const float* wr = wb + ci * 20;
#pragma unroll
                    for (int co = 0; co < KOFF; ++co)
                        acc[co] += wr[co] * val;
                }
            }
        }
    }

#pragma unroll
    for (int co = 0; co < KOFF; ++co) {
        float scale = bng[co] * rsqrtf(bnv[co] + EPSV);
        float val   = (acc[co] + ob[co] - bnm[co]) * scale + bnb[co];
        off[co * SP + v] = tanhf(val);
    }
}

// ---------------------------------------------------------------------------
// Kernel 2: snake cumsum -> bilinear(z,y) sample at integer x-column ->
//           fused (1,1,K) stride-K conv (16 -> 32) -> pre-GN output + stats
// ---------------------------------------------------------------------------
__global__ __launch_bounds__(256) void k_snake(
    const float* __restrict__ x,   const float* __restrict__ off,
    const float* __restrict__ dw,  const float* __restrict__ db,
    float* __restrict__ pre,       float* __restrict__ stats)
{
    // dw transposed to [k][ci][co] (co contiguous -> ds_read_b128 broadcast)
    __shared__ float wl[KK * CIN * COUT];   // 18 KB
    for (int i = threadIdx.x; i < KK * CIN * COUT; i += 256) {
        int co = i % COUT; int r = i / COUT; int ci = r % CIN; int k = r / CIN;
        wl[i] = dw[(co * CIN + ci) * KK + k];
    }
    __syncthreads();

    int v = blockIdx.x * 256 + threadIdx.x;
    int h = v % DD, w = (v / DD) % DD, d = v / (DD * DD);

    float acc[COUT];
#pragma unroll
    for (int co = 0; co < COUT; ++co) acc[co] = db[co];

    // Sample one k-tap: coordinates z = d + czv, y = w + cyv, x-col = h + k - 4
    // (exact integer -> wx1 = 0 always; wx0 = 0 iff clipped col lands at DD-1).
    auto process = [&](int k, float czv, float cyv) {
        int xcol = h + k - 4;
        if (xcol >= DD - 1) return;       // x-weight is exactly 0
        if (xcol < 0) xcol = 0;           // clipped low -> weight 1 at col 0

        float zf = fminf(fmaxf((float)d + czv, 0.0f), (float)(DD - 1));
        float yf = fminf(fmaxf((float)w + cyv, 0.0f), (float)(DD - 1));
        int z0 = (int)zf, y0 = (int)yf;               // zf,yf >= 0: trunc==floor
        int z1 = min(z0 + 1, DD - 1), y1 = min(y0 + 1, DD - 1);
        float wz1 = zf - (float)z0, wz0 = (float)z1 - zf;   // both 0 at top edge
        float wy1 = yf - (float)y0, wy0 = (float)y1 - yf;

        float w00 = wz0 * wy0, w01 = wz0 * wy1, w10 = wz1 * wy0, w11 = wz1 * wy1;
        int b00 = (z0 * DD + y0) * DD + xcol, b01 = (z0 * DD + y1) * DD + xcol;
        int b10 = (z1 * DD + y0) * DD + xcol, b11 = (z1 * DD + y1) * DD + xcol;

        const float* wk = &wl[k * CIN * COUT];
#pragma unroll
        for (int ci = 0; ci < CIN; ++ci) {
            const float* f = x + ci * SP;
            float s = w00 * f[b00] + w01 * f[b01] + w10 * f[b10] + w11 * f[b11];
            const float* wr = wk + ci * COUT;
#pragma unroll
            for (int co = 0; co < COUT; ++co) acc[co] += wr[co] * s;
        }
    };

    // Walk k outward from the center so the snake cumsum is incremental
    // (no runtime-indexed register arrays -> no scratch).
    process(4, 0.0f, 0.0f);
    {
        float rz = 0.0f, ry = 0.0f;
        for (int k = 3; k >= 0; --k) {
            rz += off[k * SP + v];
            ry += off[(KK + k) * SP + v];
            process(k, rz, ry);
        }
    }
    {
        float rz = 0.0f, ry = 0.0f;
        for (int k = 5; k < KK; ++k) {
            rz += off[k * SP + v];
            ry += off[(KK + k) * SP + v];
            process(k, rz, ry);
        }
    }

#pragma unroll
    for (int co = 0; co < COUT; ++co) pre[co * SP + v] = acc[co];

    // GroupNorm partial stats: per-group sum / sumsq, wave-reduce, 1 atomic/wave
#pragma unroll
    for (int g = 0; g < NG; ++g) {
        float a0 = acc[4*g], a1 = acc[4*g+1], a2 = acc[4*g+2], a3 = acc[4*g+3];
        float s  = a0 + a1 + a2 + a3;
        float ss = a0*a0 + a1*a1 + a2*a2 + a3*a3;
#pragma unroll
        for (int o = 32; o > 0; o >>= 1) {
            s  += __shfl_down(s,  o);
            ss += __shfl_down(ss, o);
        }
        if ((threadIdx.x & 63) == 0) {
            atomicAdd(&stats[g],      s);
            atomicAdd(&stats[NG + g], ss);
        }
    }
}

// ---------------------------------------------------------------------------
// Kernel 3: GroupNorm finalize + affine + ReLU (float4 I/O)
// ---------------------------------------------------------------------------
__global__ __launch_bounds__(256) void k_gn(
    const float* __restrict__ pre, const float* __restrict__ stats,
    const float* __restrict__ gamma, const float* __restrict__ beta,
    float* __restrict__ out)
{
    int idx  = blockIdx.x * 256 + threadIdx.x;   // float4 index
    int base = idx * 4;
    int c = base / SP, g = c >> 2;

    const float inv_n = 1.0f / (4.0f * (float)SP);
    float mean = stats[g] * inv_n;
    float var  = stats[NG + g] * inv_n - mean * mean;
    float rs   = rsqrtf(var + EPSV);
    float ga   = gamma[c] * rs;
    float be   = beta[c] - mean * ga;

    float4 p = *reinterpret_cast<const float4*>(pre + base);
    float4 o;
    o.x = fmaxf(p.x * ga + be, 0.0f);
    o.y = fmaxf(p.y * ga + be, 0.0f);
    o.z = fmaxf(p.z * ga + be, 0.0f);
    o.w = fmaxf(p.w * ga + be, 0.0f);
    *reinterpret_cast<float4*>(out + base) = o;
}

// ---------------------------------------------------------------------------
extern "C" void kernel_launch(void* const* d_in, const int* in_sizes, int n_in,
                              void* d_out, int out_size, void* d_ws, size_t ws_size,
                              hipStream_t stream)
{
    const float* x   = (const float*)d_in[0];
    const float* ow  = (const float*)d_in[1];
    const float* ob  = (const float*)d_in[2];
    const float* bng = (const float*)d_in[3];
    const float* bnb = (const float*)d_in[4];
    const float* bnm = (const float*)d_in[5];
    const float* bnv = (const float*)d_in[6];
    const float* dw  = (const float*)d_in[7];
    const float* db  = (const float*)d_in[8];
    const float* gng = (const float*)d_in[9];
    const float* gnb = (const float*)d_in[10];
    float* out = (float*)d_out;

    float* off   = (float*)d_ws;           // 18 * SP floats  (7.96 MB)
    float* pre   = off + (size_t)KOFF * SP; // 32 * SP floats (14.2 MB)
    float* stats = pre + (size_t)COUT * SP; // 16 floats

    k_zero  <<<1, 64, 0, stream>>>(stats);
    k_offset<<<SP / 256, 256, 0, stream>>>(x, ow, ob, bng, bnb, bnm, bnv, off);
    k_snake <<<SP / 256, 256, 0, stream>>>(x, off, dw, db, pre, stats);
    k_gn    <<<(COUT * SP / 4) / 256, 256, 0, stream>>>(pre, stats, gng, gnb, out);
}

// Round 2
// 516.820 us; speedup vs baseline: 1.0360x; 1.0360x over previous
//
#include <hip/hip_runtime.h>

#define DD    48
#define SP    (48*48*48)      // 110592 voxels
#define CIN   16
#define KOFF  18              // only first 2K offset channels are used (morph 0)
#define COUT  32
#define KK    9
#define NG    8               // groupnorm groups
#define EPSV  1e-5f
#define VPB   64              // voxels per k_snake block

// ---------------------------------------------------------------------------
// Kernel 0: zero the stats buffer (ws is poisoned 0xAA before every launch)
// ---------------------------------------------------------------------------
__global__ __launch_bounds__(64) void k_zero(float* __restrict__ stats) {
    if (threadIdx.x < 2 * NG) stats[threadIdx.x] = 0.0f;
}

// ---------------------------------------------------------------------------
// Kernel 1: offset conv 3x3x3 (SAME, 16 -> 9+9 ch) + BN(eval) + tanh
// Split over blockIdx.y (2 halves of 9 co) for 2x grid + low VGPR.
// off layout: [co][d][w][h]  (co in 0..17; 0..8 = z-offsets, 9..17 = y-offsets)
// ---------------------------------------------------------------------------
#define COH 9
__global__ __launch_bounds__(256) void k_offset(
    const float* __restrict__ x,  const float* __restrict__ ow,
    const float* __restrict__ ob, const float* __restrict__ bng,
    const float* __restrict__ bnb,const float* __restrict__ bnm,
    const float* __restrict__ bnv,float* __restrict__ off)
{
    const int cb = blockIdx.y * COH;   // 0 or 9
    // LDS weights [tap][ci][coh] padded to 12 (48B rows -> b128-friendly)
    __shared__ float wsm[27 * CIN * 12];   // 20.7 KB
    for (int i = threadIdx.x; i < 27 * CIN * COH; i += 256) {
        int co = i % COH; int r = i / COH; int ci = r % CIN; int tap = r / CIN;
        wsm[(tap * CIN + ci) * 12 + co] = ow[((cb + co) * CIN + ci) * 27 + tap];
    }
    __syncthreads();

    int v = blockIdx.x * 256 + threadIdx.x;
    int h = v % DD, w = (v / DD) % DD, d = v / (DD * DD);

    float acc[COH];
#pragma unroll
    for (int c = 0; c < COH; ++c) acc[c] = 0.0f;

#pragma unroll
    for (int kd = 0; kd < 3; ++kd) {
        int z = d + kd - 1; if ((unsigned)z >= (unsigned)DD) continue;
#pragma unroll
        for (int kw = 0; kw < 3; ++kw) {
            int yy = w + kw - 1; if ((unsigned)yy >= (unsigned)DD) continue;
#pragma unroll
            for (int kh = 0; kh < 3; ++kh) {
                int xx = h + kh - 1; if ((unsigned)xx >= (unsigned)DD) continue;
                int tap = (kd * 3 + kw) * 3 + kh;
                const float* xb = x + (z * DD + yy) * DD + xx;
                const float* wb = &wsm[tap * CIN * 12];
#pragma unroll
                for (int ci = 0; ci < CIN; ++ci) {
                    float val = xb[ci * SP];
                    const float* wr = wb + ci * 12;
#pragma unroll
                    for (int co = 0; co < COH; ++co)
                        acc[co] += wr[co] * val;
                }
            }
        }
    }

#pragma unroll
    for (int co = 0; co < COH; ++co) {
        int c = cb + co;
        float scale = bng[c] * rsqrtf(bnv[c] + EPSV);
        float val   = (acc[co] + ob[c] - bnm[c]) * scale + bnb[c];
        off[c * SP + v] = tanhf(val);
    }
}

// ---------------------------------------------------------------------------
// Kernel 2: snake cumsum -> bilinear(z,y) sample at integer x-column ->
//           fused (1,1,K) stride-K conv (16 -> 32) -> pre-GN output + stats
// Block = 256 thr = 64 voxels x 4 ci-groups (4 ci each). LDS tree-reduce.
// ---------------------------------------------------------------------------
__global__ __launch_bounds__(256) void k_snake(
    const float* __restrict__ x,   const float* __restrict__ off,
    const float* __restrict__ dw,  const float* __restrict__ db,
    float* __restrict__ pre,       float* __restrict__ stats)
{
    // dw transposed to [k][ci][co] (co contiguous; wave-uniform broadcast reads)
    __shared__ float wl[KK * CIN * COUT];          // 18 KB
    __shared__ float red[2][VPB][COUT + 1];        // 16.9 KB reduce scratch
    for (int i = threadIdx.x; i < KK * CIN * COUT; i += 256) {
        int co = i % COUT; int r = i / COUT; int ci = r % CIN; int k = r / CIN;
        wl[i] = dw[(co * CIN + ci) * KK + k];
    }
    __syncthreads();

    // XCD-aware swizzle (1728 blocks % 8 == 0 -> bijective)
    const int nwg = SP / VPB;                       // 1728
    int bid = (int)blockIdx.x;
    bid = (bid % 8) * (nwg / 8) + bid / 8;

    const int t   = threadIdx.x;
    const int vl  = t & 63;                         // voxel within block
    const int cig = t >> 6;                         // ci-group 0..3
    const int ci0 = cig * 4;
    const int v   = bid * VPB + vl;
    const int h = v % DD, w = (v / DD) % DD, d = v / (DD * DD);

    float acc[COUT];
#pragma unroll
    for (int co = 0; co < COUT; ++co) acc[co] = 0.0f;

    // One k-tap: z = d + czv, y = w + cyv, x-col = h + k - 4 (exact integer ->
    // wx1 = 0 always; contribution is exactly 0 when clipped col hits DD-1).
    auto process = [&](int k, float czv, float cyv) {
        int xcol = h + k - 4;
        if (xcol >= DD - 1) return;
        if (xcol < 0) xcol = 0;

        float zf = fminf(fmaxf((float)d + czv, 0.0f), (float)(DD - 1));
        float yf = fminf(fmaxf((float)w + cyv, 0.0f), (float)(DD - 1));
        int z0 = (int)zf, y0 = (int)yf;
        int z1 = min(z0 + 1, DD - 1), y1 = min(y0 + 1, DD - 1);
        float wz1 = zf - (float)z0, wz0 = (float)z1 - zf;
        float wy1 = yf - (float)y0, wy0 = (float)y1 - yf;

        float w00 = wz0 * wy0, w01 = wz0 * wy1, w10 = wz1 * wy0, w11 = wz1 * wy1;
        int b00 = (z0 * DD + y0) * DD + xcol, b01 = (z0 * DD + y1) * DD + xcol;
        int b10 = (z1 * DD + y0) * DD + xcol, b11 = (z1 * DD + y1) * DD + xcol;

        const float* f0 = x + ci0 * SP;
        float s[4];
#pragma unroll
        for (int c = 0; c < 4; ++c) {               // 16 independent gathers
            const float* f = f0 + c * SP;
            s[c] = w00 * f[b00] + w01 * f[b01] + w10 * f[b10] + w11 * f[b11];
        }
        const float* wk = &wl[(k * CIN + ci0) * COUT];
#pragma unroll
        for (int c = 0; c < 4; ++c) {
            const float* wr = wk + c * COUT;
#pragma unroll
            for (int co = 0; co < COUT; ++co) acc[co] += wr[co] * s[c];
        }
    };

    // Walk k outward from the center: incremental snake cumsum, no
    // runtime-indexed register arrays.
    process(4, 0.0f, 0.0f);
    {
        float rz = 0.0f, ry = 0.0f;
#pragma unroll
        for (int k = 3; k >= 0; --k) {
            rz += off[k * SP + v];
            ry += off[(KK + k) * SP + v];
            process(k, rz, ry);
        }
    }
    {
        float rz = 0.0f, ry = 0.0f;
#pragma unroll
        for (int k = 5; k < KK; ++k) {
            rz += off[k * SP + v];
            ry += off[(KK + k) * SP + v];
            process(k, rz, ry);
        }
    }

    // Tree-reduce the 4 ci-group partials in LDS
    if (cig >= 2) {
#pragma unroll
        for (int co = 0; co < COUT; ++co) red[cig - 2][vl][co] = acc[co];
    }
    __syncthreads();
    if (cig < 2) {
#pragma unroll
        for (int co = 0; co < COUT; ++co) acc[co] += red[cig][vl][co];
    }
    __syncthreads();
    if (cig == 1) {
#pragma unroll
        for (int co = 0; co < COUT; ++co) red[0][vl][co] = acc[co];
    }
    __syncthreads();

    if (cig == 0) {
#pragma unroll
        for (int co = 0; co < COUT; ++co)
            acc[co] += red[0][vl][co] + db[co];
#pragma unroll
        for (int co = 0; co < COUT; ++co) pre[co * SP + v] = acc[co];

        // GroupNorm partial stats: wave 0 only (64 lanes), 1 atomic pair/group
#pragma unroll
        for (int g = 0; g < NG; ++g) {
            float a0 = acc[4*g], a1 = acc[4*g+1], a2 = acc[4*g+2], a3 = acc[4*g+3];
            float s  = a0 + a1 + a2 + a3;
            float ss = a0*a0 + a1*a1 + a2*a2 + a3*a3;
#pragma unroll
            for (int o = 32; o > 0; o >>= 1) {
                s  += __shfl_down(s,  o);
                ss += __shfl_down(ss, o);
            }
            if (t == 0) {
                atomicAdd(&stats[g],      s);
                atomicAdd(&stats[NG + g], ss);
            }
        }
    }
}

// ---------------------------------------------------------------------------
// Kernel 3: GroupNorm finalize + affine + ReLU (float4 I/O)
// ---------------------------------------------------------------------------
__global__ __launch_bounds__(256) void k_gn(
    const float* __restrict__ pre, const float* __restrict__ stats,
    const float* __restrict__ gamma, const float* __restrict__ beta,
    float* __restrict__ out)
{
    int idx  = blockIdx.x * 256 + threadIdx.x;   // float4 index
    int base = idx * 4;
    int c = base / SP, g = c >> 2;

    const float inv_n = 1.0f / (4.0f * (float)SP);
    float mean = stats[g] * inv_n;
    float var  = stats[NG + g] * inv_n - mean * mean;
    float rs   = rsqrtf(var + EPSV);
    float ga   = gamma[c] * rs;
    float be   = beta[c] - mean * ga;

    float4 p = *reinterpret_cast<const float4*>(pre + base);
    float4 o;
    o.x = fmaxf(p.x * ga + be, 0.0f);
    o.y = fmaxf(p.y * ga + be, 0.0f);
    o.z = fmaxf(p.z * ga + be, 0.0f);
    o.w = fmaxf(p.w * ga + be, 0.0f);
    *reinterpret_cast<float4*>(out + base) = o;
}

// ---------------------------------------------------------------------------
extern "C" void kernel_launch(void* const* d_in, const int* in_sizes, int n_in,
                              void* d_out, int out_size, void* d_ws, size_t ws_size,
                              hipStream_t stream)
{
    const float* x   = (const float*)d_in[0];
    const float* ow  = (const float*)d_in[1];
    const float* ob  = (const float*)d_in[2];
    const float* bng = (const float*)d_in[3];
    const float* bnb = (const float*)d_in[4];
    const float* bnm = (const float*)d_in[5];
    const float* bnv = (const float*)d_in[6];
    const float* dw  = (const float*)d_in[7];
    const float* db  = (const float*)d_in[8];
    const float* gng = (const float*)d_in[9];
    const float* gnb = (const float*)d_in[10];
    float* out = (float*)d_out;

    float* off   = (float*)d_ws;            // 18 * SP floats  (7.96 MB)
    float* pre   = off + (size_t)KOFF * SP; // 32 * SP floats (14.2 MB)
    float* stats = pre + (size_t)COUT * SP; // 16 floats

    k_zero  <<<1, 64, 0, stream>>>(stats);
    k_offset<<<dim3(SP / 256, 2), 256, 0, stream>>>(x, ow, ob, bng, bnb, bnm, bnv, off);
    k_snake <<<SP / VPB, 256, 0, stream>>>(x, off, dw, db, pre, stats);
    k_gn    <<<(COUT * SP / 4) / 256, 256, 0, stream>>>(pre, stats, gng, gnb, out);
}

// Round 3
// 348.870 us; speedup vs baseline: 1.5348x; 1.4814x over previous
//
#include <hip/hip_runtime.h>

#define DD    48
#define SP    (48*48*48)      // 110592 voxels
#define CIN   16
#define KOFF  18              // only first 2K offset channels are used (morph 0)
#define COUT  32
#define KK    9
#define NG    8               // groupnorm groups
#define EPSV  1e-5f

// ---------------------------------------------------------------------------
// Kernel 0: zero the (padded) stats buffer: 256 floats, one counter per 64B
// ---------------------------------------------------------------------------
__global__ __launch_bounds__(256) void k_zero(float* __restrict__ stats) {
    stats[threadIdx.x] = 0.0f;
}

// ---------------------------------------------------------------------------
// Kernel 0b: transpose x [ci][v] -> xt [v][ci]  (one voxel's 16 ci = 64B line)
// lane = (voxel-in-block vb, chunk c): reads 4 strided scalars, writes float4.
// Write instr: 64 lanes x 16B contiguous = 16 fully-covered lines.
// ---------------------------------------------------------------------------
__global__ __launch_bounds__(256) void k_xt(const float* __restrict__ x,
                                            float* __restrict__ xt) {
    int t = threadIdx.x;
    int vb = t >> 2, c = t & 3;
    int v = blockIdx.x * 64 + vb;
    float4 o;
    o.x = x[(4 * c + 0) * SP + v];
    o.y = x[(4 * c + 1) * SP + v];
    o.z = x[(4 * c + 2) * SP + v];
    o.w = x[(4 * c + 3) * SP + v];
    *reinterpret_cast<float4*>(xt + v * 16 + 4 * c) = o;
}

// ---------------------------------------------------------------------------
// Kernel 1: offset conv 3x3x3 (SAME, 16 -> 9+9 ch) + BN(eval) + tanh
// (unchanged from R2 — known good; optimize with its own counters next)
// off layout: [co][d][w][h]  (co 0..8 = z-offsets, 9..17 = y-offsets)
// ---------------------------------------------------------------------------
#define COH 9
__global__ __launch_bounds__(256) void k_offset(
    const float* __restrict__ x,  const float* __restrict__ ow,
    const float* __restrict__ ob, const float* __restrict__ bng,
    const float* __restrict__ bnb,const float* __restrict__ bnm,
    const float* __restrict__ bnv,float* __restrict__ off)
{
    const int cb = blockIdx.y * COH;   // 0 or 9
    __shared__ float wsm[27 * CIN * 12];   // [tap][ci][coh pad 12], 20.7 KB
    for (int i = threadIdx.x; i < 27 * CIN * COH; i += 256) {
        int co = i % COH; int r = i / COH; int ci = r % CIN; int tap = r / CIN;
        wsm[(tap * CIN + ci) * 12 + co] = ow[((cb + co) * CIN + ci) * 27 + tap];
    }
    __syncthreads();

    int v = blockIdx.x * 256 + threadIdx.x;
    int h = v % DD, w = (v / DD) % DD, d = v / (DD * DD);

    float acc[COH];
#pragma unroll
    for (int c = 0; c < COH; ++c) acc[c] = 0.0f;

#pragma unroll
    for (int kd = 0; kd < 3; ++kd) {
        int z = d + kd - 1; if ((unsigned)z >= (unsigned)DD) continue;
#pragma unroll
        for (int kw = 0; kw < 3; ++kw) {
            int yy = w + kw - 1; if ((unsigned)yy >= (unsigned)DD) continue;
#pragma unroll
            for (int kh = 0; kh < 3; ++kh) {
                int xx = h + kh - 1; if ((unsigned)xx >= (unsigned)DD) continue;
                int tap = (kd * 3 + kw) * 3 + kh;
                const float* xb = x + (z * DD + yy) * DD + xx;
                const float* wb = &wsm[tap * CIN * 12];
#pragma unroll
                for (int ci = 0; ci < CIN; ++ci) {
                    float val = xb[ci * SP];
                    const float* wr = wb + ci * 12;
#pragma unroll
                    for (int co = 0; co < COH; ++co)
                        acc[co] += wr[co] * val;
                }
            }
        }
    }

#pragma unroll
    for (int co = 0; co < COH; ++co) {
        int c = cb + co;
        float scale = bng[c] * rsqrtf(bnv[c] + EPSV);
        float val   = (acc[co] + ob[c] - bnm[c]) * scale + bnb[c];
        off[c * SP + v] = tanhf(val);
    }
}

// ---------------------------------------------------------------------------
// Kernel 2: snake sample + fused (1,1,K)-stride-K conv (16->32) + GN stats.
// Block 256 = 64 voxels x 4 ci-chunks. Lane (vb, c): per tap loads 4 corner
// float4s from xt (wave instr = 16 full 64B lines). Chunk partials reduced
// with __shfl_xor(1,2). Output written to d_out (= pre-GN), GN in-place after.
// ---------------------------------------------------------------------------
__global__ __launch_bounds__(256, 3) void k_snake(
    const float* __restrict__ xt,  const float* __restrict__ off,
    const float* __restrict__ dw,  const float* __restrict__ db,
    float* __restrict__ pre,       float* __restrict__ stats)
{
    __shared__ float wl[KK * CIN * COUT];   // [k][ci][co], 18 KB
    __shared__ float lstat[16];
    for (int i = threadIdx.x; i < KK * CIN * COUT; i += 256) {
        int co = i % COUT; int r = i / COUT; int ci = r % CIN; int k = r / CIN;
        wl[i] = dw[(co * CIN + ci) * KK + k];
    }
    if (threadIdx.x < 16) lstat[threadIdx.x] = 0.0f;
    __syncthreads();

    // XCD-aware swizzle (1728 % 8 == 0 -> bijective)
    const int nwg = SP / 64;                 // 1728
    int bid = (int)blockIdx.x;
    bid = (bid & 7) * (nwg >> 3) + (bid >> 3);

    const int t  = threadIdx.x;
    const int c  = t & 3;                    // ci chunk (ci = 4c..4c+3)
    const int vb = t >> 2;                   // voxel in block 0..63
    const int v  = bid * 64 + vb;
    const int h = v % DD, w = (v / DD) % DD, d = v / (DD * DD);

    float acc[COUT];
#pragma unroll
    for (int co = 0; co < COUT; ++co) acc[co] = 0.0f;

    // One tap: z = d+czv, y = w+cyv, x-col = h+k-4 (exact int -> x-weight is
    // 1 unless clipped col hits DD-1, where it's exactly 0 -> skip).
    auto process = [&](int k, float czv, float cyv) {
        int xcol = h + k - 4;
        if (xcol >= DD - 1) return;
        if (xcol < 0) xcol = 0;

        float zf = fminf(fmaxf((float)d + czv, 0.0f), 47.0f);
        float yf = fminf(fmaxf((float)w + cyv, 0.0f), 47.0f);
        int z0 = (int)zf, y0 = (int)yf;
        int z1 = min(z0 + 1, 47), y1 = min(y0 + 1, 47);
        float wz1 = zf - (float)z0, wz0 = (float)z1 - zf;
        float wy1 = yf - (float)y0, wy0 = (float)y1 - yf;
        float w00 = wz0 * wy0, w01 = wz0 * wy1, w10 = wz1 * wy0, w11 = wz1 * wy1;

        const float* base = xt + 4 * c;
        const float4 A = *reinterpret_cast<const float4*>(base + ((z0 * DD + y0) * DD + xcol) * 16);
        const float4 B = *reinterpret_cast<const float4*>(base + ((z0 * DD + y1) * DD + xcol) * 16);
        const float4 C = *reinterpret_cast<const float4*>(base + ((z1 * DD + y0) * DD + xcol) * 16);
        const float4 E = *reinterpret_cast<const float4*>(base + ((z1 * DD + y1) * DD + xcol) * 16);

        float s0 = w00 * A.x + w01 * B.x + w10 * C.x + w11 * E.x;
        float s1 = w00 * A.y + w01 * B.y + w10 * C.y + w11 * E.y;
        float s2 = w00 * A.z + w01 * B.z + w10 * C.z + w11 * E.z;
        float s3 = w00 * A.w + w01 * B.w + w10 * C.w + w11 * E.w;

        const float* wk = &wl[(k * CIN + 4 * c) * COUT];
#pragma unroll
        for (int co = 0; co < COUT; ++co) acc[co] += wk[0 * COUT + co] * s0;
#pragma unroll
        for (int co = 0; co < COUT; ++co) acc[co] += wk[1 * COUT + co] * s1;
#pragma unroll
        for (int co = 0; co < COUT; ++co) acc[co] += wk[2 * COUT + co] * s2;
#pragma unroll
        for (int co = 0; co < COUT; ++co) acc[co] += wk[3 * COUT + co] * s3;
    };

    // Walk k outward from center: incremental snake cumsum.
    process(4, 0.0f, 0.0f);
    {
        float rz = 0.0f, ry = 0.0f;
#pragma unroll
        for (int k = 3; k >= 0; --k) {
            rz += off[k * SP + v];
            ry += off[(KK + k) * SP + v];
            process(k, rz, ry);
        }
    }
    {
        float rz = 0.0f, ry = 0.0f;
#pragma unroll
        for (int k = 5; k < KK; ++k) {
            rz += off[k * SP + v];
            ry += off[(KK + k) * SP + v];
            process(k, rz, ry);
        }
    }

    // Reduce the 4 ci-chunk partials (lane bits 0..1) -> all lanes get full acc
#pragma unroll
    for (int co = 0; co < COUT; ++co) {
        acc[co] += __shfl_xor(acc[co], 1);
        acc[co] += __shfl_xor(acc[co], 2);
        acc[co] += db[co];
    }

    // Store: lane chunk cc writes co = cc*8 .. cc*8+7 (static indices per arm)
#pragma unroll
    for (int cc = 0; cc < 4; ++cc) {
        if (c == cc) {
#pragma unroll
            for (int j = 0; j < 8; ++j)
                pre[(cc * 8 + j) * SP + v] = acc[cc * 8 + j];
        }
    }

    // GN stats: per-lane group sums; xor over lane bits 2..5 sums the 16
    // voxels within each chunk-class (each voxel counted exactly once).
#pragma unroll
    for (int g = 0; g < NG; ++g) {
        float a0 = acc[4*g], a1 = acc[4*g+1], a2 = acc[4*g+2], a3 = acc[4*g+3];
        float s  = a0 + a1 + a2 + a3;
        float ss = a0*a0 + a1*a1 + a2*a2 + a3*a3;
#pragma unroll
        for (int o = 4; o <= 32; o <<= 1) {
            s  += __shfl_xor(s,  o);
            ss += __shfl_xor(ss, o);
        }
        if ((t & 63) == 0) {
            atomicAdd(&lstat[g],      s);
            atomicAdd(&lstat[NG + g], ss);
        }
    }
    __syncthreads();
    if (t < 16) atomicAdd(&stats[t * 16], lstat[t]);   // padded: 1 counter/64B
}

// ---------------------------------------------------------------------------
// Kernel 3: GroupNorm finalize + affine + ReLU, IN-PLACE on d_out (float4)
// ---------------------------------------------------------------------------
__global__ __launch_bounds__(256) void k_gn(
    float* __restrict__ buf, const float* __restrict__ stats,
    const float* __restrict__ gamma, const float* __restrict__ beta)
{
    int idx  = blockIdx.x * 256 + threadIdx.x;   // float4 index
    int base = idx * 4;
    int ch = base / SP, g = ch >> 2;

    const float inv_n = 1.0f / (4.0f * (float)SP);
    float mean = stats[g * 16] * inv_n;
    float var  = stats[(NG + g) * 16] * inv_n - mean * mean;
    float rs   = rsqrtf(var + EPSV);
    float ga   = gamma[ch] * rs;
    float be   = beta[ch] - mean * ga;

    float4 p = *reinterpret_cast<const float4*>(buf + base);
    float4 o;
    o.x = fmaxf(p.x * ga + be, 0.0f);
    o.y = fmaxf(p.y * ga + be, 0.0f);
    o.z = fmaxf(p.z * ga + be, 0.0f);
    o.w = fmaxf(p.w * ga + be, 0.0f);
    *reinterpret_cast<float4*>(buf + base) = o;
}

// ---------------------------------------------------------------------------
extern "C" void kernel_launch(void* const* d_in, const int* in_sizes, int n_in,
                              void* d_out, int out_size, void* d_ws, size_t ws_size,
                              hipStream_t stream)
{
    const float* x   = (const float*)d_in[0];
    const float* ow  = (const float*)d_in[1];
    const float* ob  = (const float*)d_in[2];
    const float* bng = (const float*)d_in[3];
    const float* bnb = (const float*)d_in[4];
    const float* bnm = (const float*)d_in[5];
    const float* bnv = (const float*)d_in[6];
    const float* dw  = (const float*)d_in[7];
    const float* db  = (const float*)d_in[8];
    const float* gng = (const float*)d_in[9];
    const float* gnb = (const float*)d_in[10];
    float* out = (float*)d_out;

    float* off   = (float*)d_ws;             // 18 * SP floats (7.96 MB)
    float* xt    = off + KOFF * SP;          // 16 * SP floats (7.08 MB)
    float* stats = xt + CIN * SP;            // 256 floats (padded counters)

    k_zero  <<<1, 256, 0, stream>>>(stats);
    k_xt    <<<SP / 64, 256, 0, stream>>>(x, xt);
    k_offset<<<dim3(SP / 256, 2), 256, 0, stream>>>(x, ow, ob, bng, bnb, bnm, bnv, off);
    k_snake <<<SP / 64, 256, 0, stream>>>(xt, off, dw, db, out, stats);
    k_gn    <<<(COUT * SP / 4) / 256, 256, 0, stream>>>(out, stats, gng, gnb);
}

// Round 8
// 224.733 us; speedup vs baseline: 2.3825x; 1.5524x over previous
//
#include <hip/hip_runtime.h>

#define DD    48
#define SP    (48*48*48)      // 110592 voxels
#define CIN   16
#define KOFF  18              // only first 2K offset channels are used (morph 0)
#define COUT  32
#define KK    9
#define NG    8               // groupnorm groups
#define EPSV  1e-5f

// ---------------------------------------------------------------------------
// Kernel 0: zero the (padded) stats buffer: 256 floats, one counter per 64B
// ---------------------------------------------------------------------------
__global__ __launch_bounds__(256) void k_zero(float* __restrict__ stats) {
    stats[threadIdx.x] = 0.0f;
}

// ---------------------------------------------------------------------------
// Kernel 0b: transpose x [ci][v] -> xt [v][ci]  (one voxel's 16 ci = 64B line)
// ---------------------------------------------------------------------------
__global__ __launch_bounds__(256) void k_xt(const float* __restrict__ x,
                                            float* __restrict__ xt) {
    int t = threadIdx.x;
    int vb = t >> 2, c = t & 3;
    int v = blockIdx.x * 64 + vb;
    float4 o;
    o.x = x[(4 * c + 0) * SP + v];
    o.y = x[(4 * c + 1) * SP + v];
    o.z = x[(4 * c + 2) * SP + v];
    o.w = x[(4 * c + 3) * SP + v];
    *reinterpret_cast<float4*>(xt + v * 16 + 4 * c) = o;
}

// ---------------------------------------------------------------------------
// Kernel 1: offset conv 3x3x3 (SAME, 16 -> 9+9 ch) + BN(eval) + tanh
// On xt: block = 64 voxels x 4 ci-chunks; lane (vb,c) loads its chunk's
// float4 per tap (wave instr = 16 fully-used 64B lines); weights in LDS as
// [tap][c][co][ci4] rows (conflict-free b128, uniform-per-c broadcast).
// shfl_xor(1,2) reduces chunk partials; lanes c=0..2 write 3 co each.
// off layout: [co][v]  (co 0..8 = z-offsets, 9..17 = y-offsets)
// ---------------------------------------------------------------------------
#define COH 9
__global__ __launch_bounds__(256) void k_offset(
    const float* __restrict__ xt, const float* __restrict__ ow,
    const float* __restrict__ ob, const float* __restrict__ bng,
    const float* __restrict__ bnb,const float* __restrict__ bnm,
    const float* __restrict__ bnv,float* __restrict__ off)
{
    const int cb = blockIdx.y * COH;   // 0 or 9
    // wsm[((tap*4 + c)*9 + co)*4 + j] = w[cb+co][ci=4c+j][tap]; 15.6 KB
    __shared__ float wsm[27 * 4 * COH * 4];
    for (int i = threadIdx.x; i < 27 * CIN * COH; i += 256) {
        int co = i % COH; int r = i / COH; int ci = r % CIN; int tap = r / CIN;
        int c = ci >> 2, j = ci & 3;
        wsm[((tap * 4 + c) * COH + co) * 4 + j] = ow[((cb + co) * CIN + ci) * 27 + tap];
    }
    __syncthreads();

    const int t  = threadIdx.x;
    const int c  = t & 3;                    // ci chunk
    const int vb = t >> 2;                   // voxel in block 0..63
    const int v  = blockIdx.x * 64 + vb;
    const int h = v % DD, w = (v / DD) % DD, d = v / (DD * DD);

    float acc[COH];
#pragma unroll
    for (int co = 0; co < COH; ++co) acc[co] = 0.0f;

    const float* xc = xt + 4 * c;

#pragma unroll
    for (int kd = 0; kd < 3; ++kd) {
        int z = d + kd - 1; bool okz = (unsigned)z < (unsigned)DD;
#pragma unroll
        for (int kw = 0; kw < 3; ++kw) {
            int yy = w + kw - 1; bool oky = (unsigned)yy < (unsigned)DD;
#pragma unroll
            for (int kh = 0; kh < 3; ++kh) {
                int xx = h + kh - 1;
                if (okz && oky && (unsigned)xx < (unsigned)DD) {
                    int tap = (kd * 3 + kw) * 3 + kh;
                    float4 xv = *reinterpret_cast<const float4*>(
                        xc + ((z * DD + yy) * DD + xx) * 16);
                    const float4* wrow = reinterpret_cast<const float4*>(
                        &wsm[(tap * 4 + c) * COH * 4]);
#pragma unroll
                    for (int co = 0; co < COH; ++co) {
                        float4 w4 = wrow[co];
                        acc[co] += w4.x * xv.x + w4.y * xv.y
                                 + w4.z * xv.z + w4.w * xv.w;
                    }
                }
            }
        }
    }

    // sum the 4 ci-chunk partials (lane bits 0..1)
#pragma unroll
    for (int co = 0; co < COH; ++co) {
        acc[co] += __shfl_xor(acc[co], 1);
        acc[co] += __shfl_xor(acc[co], 2);
    }

    // lanes c = 0..2 each write 3 channels (BN eval + tanh)
#pragma unroll
    for (int c0 = 0; c0 < 3; ++c0) {
        if (c == c0) {
#pragma unroll
            for (int j = 0; j < 3; ++j) {
                int co = c0 * 3 + j;
                int ch = cb + co;
                float scale = bng[ch] * rsqrtf(bnv[ch] + EPSV);
                float val   = (acc[co] + ob[ch] - bnm[ch]) * scale + bnb[ch];
                off[ch * SP + v] = tanhf(val);
            }
        }
    }
}

// ---------------------------------------------------------------------------
// Kernel 2: snake sample + fused (1,1,K)-stride-K conv (16->32) + GN stats.
// Block 256 = 64 voxels x 4 ci-chunks. vs R3:
//  - NO min-waves launch-bound clause (R3's ",3" caused catastrophic scratch
//    spills: 381 MB writes vs 14 MB legit)
//  - wl re-laid out as [k][c][co][ci4] with 132-dword chunk stride
//    (chunk bank offset %32 = 4 -> conflict-free ds_read_b128)
//  - 2 corners live at a time (lower register pressure)
// ---------------------------------------------------------------------------
__global__ __launch_bounds__(256) void k_snake(
    const float* __restrict__ xt,  const float* __restrict__ off,
    const float* __restrict__ dw,  const float* __restrict__ db,
    float* __restrict__ pre,       float* __restrict__ stats)
{
    // wl[(k*4 + c)*132 + co*4 + j] = dw[co][ci=4c+j][k]; 19 KB
    __shared__ float wl[KK * 4 * 132];
    __shared__ float lstat[16];
    for (int i = threadIdx.x; i < KK * CIN * COUT; i += 256) {
        int co = i % COUT; int r = i / COUT; int ci = r % CIN; int k = r / CIN;
        int c = ci >> 2, j = ci & 3;
        wl[(k * 4 + c) * 132 + co * 4 + j] = dw[(co * CIN + ci) * KK + k];
    }
    if (threadIdx.x < 16) lstat[threadIdx.x] = 0.0f;
    __syncthreads();

    // XCD-aware swizzle (1728 % 8 == 0 -> bijective)
    const int nwg = SP / 64;                 // 1728
    int bid = (int)blockIdx.x;
    bid = (bid & 7) * (nwg >> 3) + (bid >> 3);

    const int t  = threadIdx.x;
    const int c  = t & 3;                    // ci chunk (ci = 4c..4c+3)
    const int vb = t >> 2;                   // voxel in block 0..63
    const int v  = bid * 64 + vb;
    const int h = v % DD, w = (v / DD) % DD, d = v / (DD * DD);

    float acc[COUT];
#pragma unroll
    for (int co = 0; co < COUT; ++co) acc[co] = 0.0f;

    // One tap: z = d+czv, y = w+cyv, x-col = h+k-4 (exact int -> x-weight is
    // 1 unless clipped col hits DD-1, where it's exactly 0 -> skip).
    auto process = [&](int k, float czv, float cyv) {
        int xcol = h + k - 4;
        if (xcol >= DD - 1) return;
        if (xcol < 0) xcol = 0;

        float zf = fminf(fmaxf((float)d + czv, 0.0f), 47.0f);
        float yf = fminf(fmaxf((float)w + cyv, 0.0f), 47.0f);
        int z0 = (int)zf, y0 = (int)yf;
        int z1 = min(z0 + 1, 47), y1 = min(y0 + 1, 47);
        float wz1 = zf - (float)z0, wz0 = (float)z1 - zf;
        float wy1 = yf - (float)y0, wy0 = (float)y1 - yf;
        float w00 = wz0 * wy0, w01 = wz0 * wy1, w10 = wz1 * wy0, w11 = wz1 * wy1;

        const float* base = xt + 4 * c;
        float s0, s1, s2, s3;
        {
            const float4 A = *reinterpret_cast<const float4*>(base + ((z0 * DD + y0) * DD + xcol) * 16);
            const float4 B = *reinterpret_cast<const float4*>(base + ((z0 * DD + y1) * DD + xcol) * 16);
            s0 = w00 * A.x + w01 * B.x;
            s1 = w00 * A.y + w01 * B.y;
            s2 = w00 * A.z + w01 * B.z;
            s3 = w00 * A.w + w01 * B.w;
        }
        {
            const float4 C = *reinterpret_cast<const float4*>(base + ((z1 * DD + y0) * DD + xcol) * 16);
            const float4 E = *reinterpret_cast<const float4*>(base + ((z1 * DD + y1) * DD + xcol) * 16);
            s0 += w10 * C.x + w11 * E.x;
            s1 += w10 * C.y + w11 * E.y;
            s2 += w10 * C.z + w11 * E.z;
            s3 += w10 * C.w + w11 * E.w;
        }

        const float4* wrow = reinterpret_cast<const float4*>(&wl[(k * 4 + c) * 132]);
#pragma unroll
        for (int co = 0; co < COUT; ++co) {
            float4 w4 = wrow[co];
            acc[co] += w4.x * s0 + w4.y * s1 + w4.z * s2 + w4.w * s3;
        }
    };

    // Walk k outward from center: incremental snake cumsum.
    process(4, 0.0f, 0.0f);
    {
        float rz = 0.0f, ry = 0.0f;
#pragma unroll
        for (int k = 3; k >= 0; --k) {
            rz += off[k * SP + v];
            ry += off[(KK + k) * SP + v];
            process(k, rz, ry);
        }
    }
    {
        float rz = 0.0f, ry = 0.0f;
#pragma unroll
        for (int k = 5; k < KK; ++k) {
            rz += off[k * SP + v];
            ry += off[(KK + k) * SP + v];
            process(k, rz, ry);
        }
    }

    // Reduce the 4 ci-chunk partials (lane bits 0..1) -> all lanes get full acc
#pragma unroll
    for (int co = 0; co < COUT; ++co) {
        acc[co] += __shfl_xor(acc[co], 1);
        acc[co] += __shfl_xor(acc[co], 2);
        acc[co] += db[co];
    }

    // Store: lane chunk cc writes co = cc*8 .. cc*8+7 (static indices per arm)
#pragma unroll
    for (int cc = 0; cc < 4; ++cc) {
        if (c == cc) {
#pragma unroll
            for (int j = 0; j < 8; ++j)
                pre[(cc * 8 + j) * SP + v] = acc[cc * 8 + j];
        }
    }

    // GN stats: per-lane group sums; xor over lane bits 2..5 sums the 16
    // voxels within each chunk-class (each voxel counted exactly once).
#pragma unroll
    for (int g = 0; g < NG; ++g) {
        float a0 = acc[4*g], a1 = acc[4*g+1], a2 = acc[4*g+2], a3 = acc[4*g+3];
        float s  = a0 + a1 + a2 + a3;
        float ss = a0*a0 + a1*a1 + a2*a2 + a3*a3;
#pragma unroll
        for (int o = 4; o <= 32; o <<= 1) {
            s  += __shfl_xor(s,  o);
            ss += __shfl_xor(ss, o);
        }
        if ((t & 63) == 0) {
            atomicAdd(&lstat[g],      s);
            atomicAdd(&lstat[NG + g], ss);
        }
    }
    __syncthreads();
    if (t < 16) atomicAdd(&stats[t * 16], lstat[t]);   // padded: 1 counter/64B
}

// ---------------------------------------------------------------------------
// Kernel 3: GroupNorm finalize + affine + ReLU, IN-PLACE on d_out (float4)
// ---------------------------------------------------------------------------
__global__ __launch_bounds__(256) void k_gn(
    float* __restrict__ buf, const float* __restrict__ stats,
    const float* __restrict__ gamma, const float* __restrict__ beta)
{
    int idx  = blockIdx.x * 256 + threadIdx.x;   // float4 index
    int base = idx * 4;
    int ch = base / SP, g = ch >> 2;

    const float inv_n = 1.0f / (4.0f * (float)SP);
    float mean = stats[g * 16] * inv_n;
    float var  = stats[(NG + g) * 16] * inv_n - mean * mean;
    float rs   = rsqrtf(var + EPSV);
    float ga   = gamma[ch] * rs;
    float be   = beta[ch] - mean * ga;

    float4 p = *reinterpret_cast<const float4*>(buf + base);
    float4 o;
    o.x = fmaxf(p.x * ga + be, 0.0f);
    o.y = fmaxf(p.y * ga + be, 0.0f);
    o.z = fmaxf(p.z * ga + be, 0.0f);
    o.w = fmaxf(p.w * ga + be, 0.0f);
    *reinterpret_cast<float4*>(buf + base) = o;
}

// ---------------------------------------------------------------------------
extern "C" void kernel_launch(void* const* d_in, const int* in_sizes, int n_in,
                              void* d_out, int out_size, void* d_ws, size_t ws_size,
                              hipStream_t stream)
{
    const float* x   = (const float*)d_in[0];
    const float* ow  = (const float*)d_in[1];
    const float* ob  = (const float*)d_in[2];
    const float* bng = (const float*)d_in[3];
    const float* bnb = (const float*)d_in[4];
    const float* bnm = (const float*)d_in[5];
    const float* bnv = (const float*)d_in[6];
    const float* dw  = (const float*)d_in[7];
    const float* db  = (const float*)d_in[8];
    const float* gng = (const float*)d_in[9];
    const float* gnb = (const float*)d_in[10];
    float* out = (float*)d_out;

    float* off   = (float*)d_ws;             // 18 * SP floats (7.96 MB)
    float* xt    = off + KOFF * SP;          // 16 * SP floats (7.08 MB)
    float* stats = xt + CIN * SP;            // 256 floats (padded counters)

    k_zero  <<<1, 256, 0, stream>>>(stats);
    k_xt    <<<SP / 64, 256, 0, stream>>>(x, xt);
    k_offset<<<dim3(SP / 64, 2), 256, 0, stream>>>(xt, ow, ob, bng, bnb, bnm, bnv, off);
    k_snake <<<SP / 64, 256, 0, stream>>>(xt, off, dw, db, out, stats);
    k_gn    <<<(COUT * SP / 4) / 256, 256, 0, stream>>>(out, stats, gng, gnb);
}